// Round 1
// baseline (894.908 us; speedup 1.0000x reference)
//
#include <hip/hip_runtime.h>
#include <hip/hip_bf16.h>

// Sizes fixed by the reference problem.
#define BD 256      // d_model
#define NBANK 3
#define NLP 48      // NB*NL*P = 3*2*8 basis vectors
#define NHEAD 4
#define HDIM 64

// ws layout (floats)
#define WS_W1T 0            // [256][64]  : [d][slot]  slot w*16+i -> j=w*13+i ; j<3 = Wg row, j=3+nlp = Pq'/16
#define WS_KWT 16384        // [256][4][64]: [d][h][0..47]=KW'/8, [48]=KWb'/8
#define WS_CT  81920        // [256][4][64]: [d][h][nlp]= m*VO
#define WS_PT  147456       // [256][64]  : [d][nlp] = (1-m)*prims
#define WS_OB  163840       // [256]      : m*(bv@out_w.T + out_b)
#define WS_BQK 164096       // [4][64]    : [h][nlp]=bq.Kp/8, [48]=bq.bk/8
#define WS_LW  164352       // [8]        : softmax(level_weights)
#define WS_KP  164608       // [48][256]
#define WS_VP  176896       // [48][256]
#define WS_FLOATS 189184

__global__ void hpm_k0a(const float* __restrict__ prims, const float* __restrict__ lvlw,
                        const float* __restrict__ wq, const float* __restrict__ wg,
                        const float* __restrict__ ipw, const float* __restrict__ ipb,
                        const float* __restrict__ outw, const float* __restrict__ outb,
                        const float* __restrict__ caw, float* __restrict__ ws) {
  float* W1T = ws + WS_W1T;
  float* PT  = ws + WS_PT;
  float* OB  = ws + WS_OB;
  float* LW  = ws + WS_LW;
  float* Kp  = ws + WS_KP;
  float* Vp  = ws + WS_VP;
  int t = threadIdx.x;
  int blk = blockIdx.x;
  float m = 1.0f / (1.0f + __expf(-caw[0]));
  if (blk < 48) {                    // Kp[nlp][o] = prims[nlp] . Wk_row(o)
    const float* pr = prims + blk * BD;
    const float* wr = ipw + (size_t)(256 + t) * BD;
    float s = 0.f;
    for (int d = 0; d < BD; ++d) s = fmaf(pr[d], wr[d], s);
    Kp[blk * BD + t] = s;
  } else if (blk < 96) {             // Vp[nlp][o] = prims[nlp] . Wv_row(o)
    int nlp = blk - 48;
    const float* pr = prims + nlp * BD;
    const float* wr = ipw + (size_t)(512 + t) * BD;
    float s = 0.f;
    for (int d = 0; d < BD; ++d) s = fmaf(pr[d], wr[d], s);
    Vp[nlp * BD + t] = s;
  } else if (blk < 144) {            // Pq'[nlp][d] = (prims[nlp] @ Wq[n]) / 16 -> W1T slot
    int nlp = blk - 96;
    int n = nlp >> 4;
    const float* pr = prims + nlp * BD;
    const float* wqn = wq + (size_t)n * BD * BD;
    float s = 0.f;
    for (int o = 0; o < BD; ++o) s = fmaf(pr[o], wqn[o * BD + t], s);
    int j = 3 + nlp;
    int wv = j / 13, i = j - wv * 13;
    W1T[t * 64 + wv * 16 + i] = s * (1.0f / 16.0f);
  } else {                           // blk==144: Wg rows, pads, PT, OB, LW. thread = d
    float* row = W1T + t * 64;
    row[13] = 0.f; row[14] = 0.f; row[15] = 0.f;
    row[29] = 0.f; row[30] = 0.f; row[31] = 0.f;
    row[45] = 0.f; row[46] = 0.f; row[47] = 0.f;
    row[60] = 0.f; row[61] = 0.f; row[62] = 0.f; row[63] = 0.f;
    row[0] = wg[0 * BD + t];
    row[1] = wg[1 * BD + t];
    row[2] = wg[2 * BD + t];
    for (int nlp = 0; nlp < NLP; ++nlp) PT[t * 64 + nlp] = (1.0f - m) * prims[nlp * BD + t];
    for (int j = NLP; j < 64; ++j) PT[t * 64 + j] = 0.f;
    const float* bv = ipb + 512;
    const float* orow = outw + (size_t)t * BD;
    float s = 0.f;
    for (int o = 0; o < BD; ++o) s = fmaf(bv[o], orow[o], s);
    OB[t] = m * (s + outb[t]);
    if (t == 0) {
      for (int n = 0; n < 3; ++n) {
        float a = lvlw[n * 2], b = lvlw[n * 2 + 1];
        float mx = fmaxf(a, b);
        float ea = __expf(a - mx), eb = __expf(b - mx);
        float inv = 1.0f / (ea + eb);
        LW[n * 2] = ea * inv;
        LW[n * 2 + 1] = eb * inv;
      }
      LW[6] = 0.f; LW[7] = 0.f;
    }
  }
}

__global__ void hpm_k0b(const float* __restrict__ ipw, const float* __restrict__ ipb,
                        const float* __restrict__ outw, const float* __restrict__ caw,
                        float* __restrict__ ws) {
  float* KWT = ws + WS_KWT;
  float* CT  = ws + WS_CT;
  float* BQK = ws + WS_BQK;
  const float* Kp = ws + WS_KP;
  const float* Vp = ws + WS_VP;
  int t = threadIdx.x;
  int blk = blockIdx.x;
  float m = 1.0f / (1.0f + __expf(-caw[0]));
  if (blk < 192) {                   // KW'[d][h][nlp] = (1/8) sum_{o in h} W0[o][d]*Kp[nlp][o]
    int h = blk / 48, nlp = blk % 48;
    const float* kpr = Kp + nlp * BD + h * HDIM;
    float s = 0.f;
    for (int o = 0; o < HDIM; ++o) s = fmaf(ipw[(size_t)(h * HDIM + o) * BD + t], kpr[o], s);
    KWT[(t * 4 + h) * 64 + nlp] = s * 0.125f;
  } else if (blk < 196) {            // KWb'[d][h] at slot 48
    int h = blk - 192;
    const float* bk = ipb + 256 + h * HDIM;
    float s = 0.f;
    for (int o = 0; o < HDIM; ++o) s = fmaf(ipw[(size_t)(h * HDIM + o) * BD + t], bk[o], s);
    KWT[(t * 4 + h) * 64 + 48] = s * 0.125f;
  } else if (blk < 388) {            // CT[d][h][nlp] = m * sum_{o in h} Vp[nlp][o]*out_w[d][o]
    int q = blk - 196;
    int h = q / 48, nlp = q % 48;
    const float* vpr = Vp + nlp * BD + h * HDIM;
    const float* orow = outw + (size_t)t * BD + h * HDIM;
    float s = 0.f;
    for (int o = 0; o < HDIM; ++o) s = fmaf(vpr[o], orow[o], s);
    CT[(t * 4 + h) * 64 + nlp] = m * s;
  } else {                           // BQK
    if (t < 196) {
      int h = t / 49, j = t % 49;
      const float* bq = ipb + h * HDIM;
      float s = 0.f;
      if (j < 48) {
        const float* kpr = Kp + j * BD + h * HDIM;
        for (int o = 0; o < HDIM; ++o) s = fmaf(bq[o], kpr[o], s);
      } else {
        const float* bk = ipb + 256 + h * HDIM;
        for (int o = 0; o < HDIM; ++o) s = fmaf(bq[o], bk[o], s);
      }
      BQK[h * 64 + j] = s * 0.125f;
    }
  }
}

// Main fused kernel: 64 rows/block, 4 waves. lane = row; waves split work.
__global__ __launch_bounds__(256, 3) void hpm_k1(
    const float* __restrict__ z, const float* __restrict__ bg,
    const float* __restrict__ lng, const float* __restrict__ lnb,
    const float* __restrict__ ws, float* __restrict__ out) {
  const float* W1T = ws + WS_W1T;
  const float* KWT = ws + WS_KWT;
  const float* CT  = ws + WS_CT;
  const float* PT  = ws + WS_PT;
  const float* OB  = ws + WS_OB;
  const float* BQK = ws + WS_BQK;
  const float* LW  = ws + WS_LW;

  __shared__ float zb[64][65];   // z chunk staging (stride 65: <=2 lanes/bank)
  __shared__ float x1[64][53];   // phase-A accumulator exchange
  __shared__ float x2[64][21];   // att exchange [0..11] + LN stats [12..19]

  const int tid = threadIdx.x;
  const int l = tid & 63;
  const int w = __builtin_amdgcn_readfirstlane(tid >> 6);  // uniform -> s_load weights
  const int r0 = blockIdx.x * 64;
  const size_t row = (size_t)(r0 + l);

  // ---------------- Phase A: logits (j<3) + scores (j=3+nlp), 13 j per wave ----------------
  float acc[13];
#pragma unroll
  for (int i = 0; i < 13; ++i) acc[i] = 0.f;
  if (w == 0) { acc[0] = bg[0]; acc[1] = bg[1]; acc[2] = bg[2]; }

  for (int cg = 0; cg < 4; ++cg) {
#pragma unroll
    for (int i = 0; i < 4; ++i) {
      int f = tid + i * 256;
      int srow = f >> 4, seg = f & 15;
      const float4 v = *reinterpret_cast<const float4*>(z + (size_t)(r0 + srow) * BD + cg * 64 + seg * 4);
      zb[srow][seg * 4 + 0] = v.x; zb[srow][seg * 4 + 1] = v.y;
      zb[srow][seg * 4 + 2] = v.z; zb[srow][seg * 4 + 3] = v.w;
    }
    __syncthreads();
    const float* wp0 = W1T + cg * 64 * 64 + w * 16;
    for (int d = 0; d < 64; ++d) {
      float zd = zb[l][d];
      const float* wp = wp0 + d * 64;
#pragma unroll
      for (int i = 0; i < 13; ++i) acc[i] = fmaf(zd, wp[i], acc[i]);
    }
    __syncthreads();
  }
#pragma unroll
  for (int i = 0; i < 13; ++i) x1[l][w * 13 + i] = acc[i];
  __syncthreads();

  float s[51];
#pragma unroll
  for (int j = 0; j < 51; ++j) s[j] = x1[l][j];

  // router: softmax(3) -> top2 -> renorm (tie-break matches jax top_k: lower index wins)
  float r_[3];
  {
    float mx = fmaxf(s[0], fmaxf(s[1], s[2]));
    float e0 = __expf(s[0] - mx), e1 = __expf(s[1] - mx), e2 = __expf(s[2] - mx);
    float inv = 1.0f / (e0 + e1 + e2);
    float p0 = e0 * inv, p1 = e1 * inv, p2 = e2 * inv;
    int drop = (p2 <= p1 && p2 <= p0) ? 2 : ((p1 <= p0) ? 1 : 0);
    float a = (drop == 0) ? 0.f : p0;
    float b = (drop == 1) ? 0.f : p1;
    float c = (drop == 2) ? 0.f : p2;
    float den = 1.0f / (a + b + c + 1e-9f);
    r_[0] = a * den; r_[1] = b * den; r_[2] = c * den;
  }
  // alpha softmax per (n,lvl) over 8 prims; c = alpha * lw
  float c_[48];
#pragma unroll
  for (int n = 0; n < 3; ++n) {
#pragma unroll
    for (int lv = 0; lv < 2; ++lv) {
      float sc[8];
      float mx = -1e30f;
#pragma unroll
      for (int p = 0; p < 8; ++p) { sc[p] = s[3 + n * 16 + lv * 8 + p]; mx = fmaxf(mx, sc[p]); }
      float sum = 0.f;
#pragma unroll
      for (int p = 0; p < 8; ++p) { sc[p] = __expf(sc[p] - mx); sum += sc[p]; }
      float lwv = LW[n * 2 + lv] / sum;
#pragma unroll
      for (int p = 0; p < 8; ++p) c_[n * 16 + lv * 8 + p] = sc[p] * lwv;
    }
  }

  // ---------------- Phase B: attention logits, head = w ----------------
  float atk[3] = {0.f, 0.f, 0.f};
  float cacc = 0.f;
  for (int cg = 0; cg < 4; ++cg) {
#pragma unroll
    for (int i = 0; i < 4; ++i) {
      int f = tid + i * 256;
      int srow = f >> 4, seg = f & 15;
      const float4 v = *reinterpret_cast<const float4*>(z + (size_t)(r0 + srow) * BD + cg * 64 + seg * 4);
      zb[srow][seg * 4 + 0] = v.x; zb[srow][seg * 4 + 1] = v.y;
      zb[srow][seg * 4 + 2] = v.z; zb[srow][seg * 4 + 3] = v.w;
    }
    __syncthreads();
    const float* wp0 = KWT + (size_t)(cg * 64 * 4 + w) * 64;
    for (int d = 0; d < 64; ++d) {
      float zd = zb[l][d];
      const float* wp = wp0 + (size_t)d * 4 * 64;
#pragma unroll
      for (int n = 0; n < 3; ++n) {
        float t = 0.f;
#pragma unroll
        for (int i = 0; i < 16; ++i) t = fmaf(c_[n * 16 + i], wp[n * 16 + i], t);
        atk[n] = fmaf(zd, t, atk[n]);
      }
      cacc = fmaf(zd, wp[48], cacc);
    }
    __syncthreads();
  }
  {
    const float* bqh = BQK + w * 64;
#pragma unroll
    for (int n = 0; n < 3; ++n) {
      float t = bqh[48];
#pragma unroll
      for (int i = 0; i < 16; ++i) t = fmaf(c_[n * 16 + i], bqh[n * 16 + i], t);
      atk[n] += cacc + t;
    }
    float mx = fmaxf(atk[0], fmaxf(atk[1], atk[2]));
    float e0 = __expf(atk[0] - mx), e1 = __expf(atk[1] - mx), e2 = __expf(atk[2] - mx);
    float inv = 1.0f / (e0 + e1 + e2);
    atk[0] = e0 * inv; atk[1] = e1 * inv; atk[2] = e2 * inv;
  }
  x2[l][w * 3 + 0] = atk[0];
  x2[l][w * 3 + 1] = atk[1];
  x2[l][w * 3 + 2] = atk[2];
  __syncthreads();
  float att[12];
#pragma unroll
  for (int j = 0; j < 12; ++j) att[j] = x2[l][j];

  // ---------------- Phase C: y[d] for d in [w*64, w*64+64), fused LN ----------------
  float sum = 0.f, ss = 0.f;
  for (int sub = 0; sub < 8; ++sub) {
    float yv[8];
#pragma unroll
    for (int q = 0; q < 8; ++q) {
      int Dd = w * 64 + sub * 8 + q;
      const float* cw = CT + (size_t)Dd * 4 * 64;
      float a = OB[Dd];
#pragma unroll
      for (int h = 0; h < 4; ++h) {
        const float* ch = cw + h * 64;
#pragma unroll
        for (int n = 0; n < 3; ++n) {
          float t = 0.f;
#pragma unroll
          for (int i = 0; i < 16; ++i) t = fmaf(c_[n * 16 + i], ch[n * 16 + i], t);
          a = fmaf(att[h * 3 + n], t, a);
        }
      }
      const float* pw = PT + (size_t)Dd * 64;
#pragma unroll
      for (int n = 0; n < 3; ++n) {
        float t = 0.f;
#pragma unroll
        for (int i = 0; i < 16; ++i) t = fmaf(c_[n * 16 + i], pw[n * 16 + i], t);
        a = fmaf(r_[n], t, a);
      }
      yv[q] = a;
      sum += a;
      ss = fmaf(a, a, ss);
    }
    float* op = out + row * BD + w * 64 + sub * 8;
#pragma unroll
    for (int q4 = 0; q4 < 2; ++q4) {
      float4 v;
      v.x = yv[q4 * 4 + 0]; v.y = yv[q4 * 4 + 1];
      v.z = yv[q4 * 4 + 2]; v.w = yv[q4 * 4 + 3];
      *reinterpret_cast<float4*>(op + q4 * 4) = v;   // raw (pre-LN) y
    }
  }
  x2[l][12 + w * 2 + 0] = sum;
  x2[l][12 + w * 2 + 1] = ss;
  __syncthreads();
  float ts = 0.f, tss = 0.f;
#pragma unroll
  for (int i = 0; i < 4; ++i) { ts += x2[l][12 + i * 2]; tss += x2[l][12 + i * 2 + 1]; }
  float mu = ts * (1.0f / 256.0f);
  float var = tss * (1.0f / 256.0f) - mu * mu;
  float rstd = rsqrtf(var + 1e-5f);
  float* op0 = out + row * BD + w * 64;
#pragma unroll
  for (int q4 = 0; q4 < 16; ++q4) {
    float4 v = *reinterpret_cast<float4*>(op0 + q4 * 4);  // same-thread re-read of own raw writes
    int Dd = w * 64 + q4 * 4;
    v.x = (v.x - mu) * rstd * lng[Dd + 0] + lnb[Dd + 0];
    v.y = (v.y - mu) * rstd * lng[Dd + 1] + lnb[Dd + 1];
    v.z = (v.z - mu) * rstd * lng[Dd + 2] + lnb[Dd + 2];
    v.w = (v.w - mu) * rstd * lng[Dd + 3] + lnb[Dd + 3];
    *reinterpret_cast<float4*>(op0 + q4 * 4) = v;
  }
}

extern "C" void kernel_launch(void* const* d_in, const int* in_sizes, int n_in,
                              void* d_out, int out_size, void* d_ws, size_t ws_size,
                              hipStream_t stream) {
  const float* z     = (const float*)d_in[0];
  const float* prims = (const float*)d_in[1];
  const float* lvlw  = (const float*)d_in[2];
  const float* wq    = (const float*)d_in[3];
  const float* wg    = (const float*)d_in[4];
  const float* bg    = (const float*)d_in[5];
  const float* ipw   = (const float*)d_in[6];
  const float* ipb   = (const float*)d_in[7];
  const float* outw  = (const float*)d_in[8];
  const float* outb  = (const float*)d_in[9];
  const float* lng   = (const float*)d_in[10];
  const float* lnb   = (const float*)d_in[11];
  const float* caw   = (const float*)d_in[12];
  float* ws  = (float*)d_ws;
  float* out = (float*)d_out;

  if (ws_size < (size_t)WS_FLOATS * sizeof(float)) return;  // need ~740 KB scratch

  const int B = in_sizes[0] / BD;   // 65536
  hpm_k0a<<<145, 256, 0, stream>>>(prims, lvlw, wq, wg, ipw, ipb, outw, outb, caw, ws);
  hpm_k0b<<<389, 256, 0, stream>>>(ipw, ipb, outw, caw, ws);
  hpm_k1<<<B / 64, 256, 0, stream>>>(z, bg, lng, lnb, ws, out);
}

// Round 3
// 248.771 us; speedup vs baseline: 3.5973x; 3.5973x over previous
//
#include <hip/hip_runtime.h>

#define BD 256

// ---- ws offsets (in floats), total 181776 floats = 727 KB (fits proven >=740 KB ws) ----
#define WS_PQ   0         // [48][256]   (prims@Wq)/16
#define WS_KWT  12288     // [256][4][49] KW'/8 (j=0..47) + bias col j=48
#define WS_CT   62464     // [256][4][48] m*VO
#define WS_PT   111616    // [256][48]   (1-m)*prims^T
#define WS_OB   123904    // [256]
#define WS_BQK  124160    // [4][64]     bq-side constants /8
#define WS_LW   124416    // [16] softmax(level_weights)
#define WS_KP   124432    // [48][256]   dead after k0b
#define WS_VP   136720    // [48][256]   dead after k0b
#define WS_WZF  149008    // 65536 halfs: Wz bf16 B-fragments
#define WS_MF   0         // 65536 halfs: M  bf16 B-fragments (overlays PQ/KWT, dead after k0c1)
#define WS_TOTAL 181776

typedef __bf16 bf16x8 __attribute__((ext_vector_type(8)));
typedef float  f32x4  __attribute__((ext_vector_type(4)));

__device__ __forceinline__ float bf2f(unsigned short u) {
  union { float f; unsigned int i; } c; c.i = ((unsigned int)u) << 16; return c.f;
}
__device__ __forceinline__ unsigned short f2bf(float f) {
  union { float f; unsigned int i; } c; c.f = f;
  unsigned int x = c.i;
  unsigned int r = (x + 0x7fffu + ((x >> 16) & 1u)) >> 16;
  return (unsigned short)r;
}

__global__ void hpm_k0a(const float* __restrict__ prims, const float* __restrict__ lvlw,
                        const float* __restrict__ wq, const float* __restrict__ ipw,
                        const float* __restrict__ ipb, const float* __restrict__ outw,
                        const float* __restrict__ outb, const float* __restrict__ caw,
                        float* __restrict__ ws) {
  int t = threadIdx.x, blk = blockIdx.x;
  float m = 1.0f / (1.0f + __expf(-caw[0]));
  if (blk < 48) {                    // Kp[nlp][o] = prims[nlp] . Wk_row(o)
    const float* pr = prims + blk * BD;
    const float* wr = ipw + (size_t)(256 + t) * BD;
    float s = 0.f;
    for (int d = 0; d < BD; ++d) s = fmaf(pr[d], wr[d], s);
    ws[WS_KP + blk * BD + t] = s;
  } else if (blk < 96) {             // Vp[nlp][o]
    int nlp = blk - 48;
    const float* pr = prims + nlp * BD;
    const float* wr = ipw + (size_t)(512 + t) * BD;
    float s = 0.f;
    for (int d = 0; d < BD; ++d) s = fmaf(pr[d], wr[d], s);
    ws[WS_VP + nlp * BD + t] = s;
  } else if (blk < 144) {            // PQ[nlp][d] = (prims@Wq[n])/16
    int nlp = blk - 96, n = nlp >> 4;
    const float* pr = prims + nlp * BD;
    const float* wqn = wq + (size_t)n * BD * BD;
    float s = 0.f;
    for (int o = 0; o < BD; ++o) s = fmaf(pr[o], wqn[o * BD + t], s);
    ws[WS_PQ + nlp * BD + t] = s * (1.0f / 16.0f);
  } else {                           // PT, OB, LW
    for (int nlp = 0; nlp < 48; ++nlp) ws[WS_PT + t * 48 + nlp] = (1.0f - m) * prims[nlp * BD + t];
    const float* bv = ipb + 512;
    const float* orow = outw + (size_t)t * BD;
    float s = 0.f;
    for (int o = 0; o < BD; ++o) s = fmaf(bv[o], orow[o], s);
    ws[WS_OB + t] = m * (s + outb[t]);
    if (t == 0) {
      for (int n = 0; n < 3; ++n) {
        float a = lvlw[n * 2], b = lvlw[n * 2 + 1];
        float mx = fmaxf(a, b);
        float ea = __expf(a - mx), eb = __expf(b - mx);
        float inv = 1.0f / (ea + eb);
        ws[WS_LW + n * 2] = ea * inv;
        ws[WS_LW + n * 2 + 1] = eb * inv;
      }
      ws[WS_LW + 6] = 0.f; ws[WS_LW + 7] = 0.f;
    }
  }
}

__global__ void hpm_k0b(const float* __restrict__ ipw, const float* __restrict__ ipb,
                        const float* __restrict__ outw, const float* __restrict__ caw,
                        float* __restrict__ ws) {
  int t = threadIdx.x, blk = blockIdx.x;
  float m = 1.0f / (1.0f + __expf(-caw[0]));
  const float* Kp = ws + WS_KP;
  const float* Vp = ws + WS_VP;
  if (blk < 192) {                   // KW'[d][h][nlp] = (1/8) sum_{o in h} W0[o][d]*Kp[nlp][o]
    int h = blk / 48, nlp = blk % 48;
    const float* kpr = Kp + nlp * BD + h * 64;
    float s = 0.f;
    for (int o = 0; o < 64; ++o) s = fmaf(ipw[(size_t)(h * 64 + o) * BD + t], kpr[o], s);
    ws[WS_KWT + (t * 4 + h) * 49 + nlp] = s * 0.125f;
  } else if (blk < 196) {            // bias col j=48
    int h = blk - 192;
    const float* bk = ipb + 256 + h * 64;
    float s = 0.f;
    for (int o = 0; o < 64; ++o) s = fmaf(ipw[(size_t)(h * 64 + o) * BD + t], bk[o], s);
    ws[WS_KWT + (t * 4 + h) * 49 + 48] = s * 0.125f;
  } else if (blk < 388) {            // CT[d][h][nlp] = m * sum_{o in h} Vp[nlp][o]*out_w[d][o]
    int q = blk - 196;
    int h = q / 48, nlp = q % 48;
    const float* vpr = Vp + nlp * BD + h * 64;
    const float* orow = outw + (size_t)t * BD + h * 64;
    float s = 0.f;
    for (int o = 0; o < 64; ++o) s = fmaf(vpr[o], orow[o], s);
    ws[WS_CT + (t * 4 + h) * 48 + nlp] = m * s;
  } else {                           // BQK
    if (t < 196) {
      int h = t / 49, j = t % 49;
      const float* bq = ipb + h * 64;
      float s = 0.f;
      if (j < 48) {
        const float* kpr = Kp + j * BD + h * 64;
        for (int o = 0; o < 64; ++o) s = fmaf(bq[o], kpr[o], s);
      } else {
        const float* bk = ipb + 256 + h * 64;
        for (int o = 0; o < 64; ++o) s = fmaf(bq[o], bk[o], s);
      }
      ws[WS_BQK + h * 64 + j] = s * 0.125f;
    }
  }
}

// B-fragment pack: half index e = ((kt*16+ct)*64 + lane)*8 + i
//   holds X[k = kt*32+(lane>>4)*8+i][col = ct*16+(lane&15)]
__global__ void hpm_k0c1(const float* __restrict__ wg, float* __restrict__ ws) {
  int e = blockIdx.x * 256 + threadIdx.x;   // 0..65535
  int i = e & 7, lane = (e >> 3) & 63, tile = e >> 9;
  int kt = tile >> 4, ct = tile & 15;
  int k = kt * 32 + (lane >> 4) * 8 + i;
  int col = ct * 16 + (lane & 15);
  float v;
  if (col < 3) v = wg[col * BD + k];
  else if (col < 51) v = ws[WS_PQ + (col - 3) * BD + k];
  else if (col < 247) { int j2 = col - 51; int h = j2 / 49; int jj = j2 - h * 49;
                        v = ws[WS_KWT + (k * 4 + h) * 49 + jj]; }
  else v = 0.f;
  ((unsigned short*)(ws + WS_WZF))[e] = f2bf(v);
}

__global__ void hpm_k0c2(float* __restrict__ ws) {
  int e = blockIdx.x * 256 + threadIdx.x;   // 0..65535
  int i = e & 7, lane = (e >> 3) & 63, tile = e >> 9;
  int kt = tile >> 4, ct = tile & 15;
  int k = kt * 32 + (lane >> 4) * 8 + i;
  int col = ct * 16 + (lane & 15);
  float v;
  if (k < 192) v = ws[WS_CT + (col * 4 + k / 48) * 48 + (k % 48)];
  else if (k < 240) v = ws[WS_PT + col * 48 + (k - 192)];
  else if (k == 240) v = ws[WS_OB + col];
  else v = 0.f;
  ((unsigned short*)(ws + WS_MF))[e] = f2bf(v);
}

// Main fused kernel: 32 rows/block, 4 waves split N. GEMM1 -> epilogue -> GEMM3 -> LN.
__global__ __launch_bounds__(256) void hpm_main(
    const float* __restrict__ z, const float* __restrict__ wg,
    const float* __restrict__ bg, const float* __restrict__ lng,
    const float* __restrict__ lnb, const float* __restrict__ ws,
    float* __restrict__ out) {
  __shared__ unsigned short zs[32 * 40];   // z ktile bf16, 80B row stride
  __shared__ unsigned short U[16384];      // phase A: T [32][264]; phase B: Gh@0 / Gl@8192 (XOR-swizzled)
  __shared__ float cbuf[32 * 48];
  __shared__ float rbuf[32 * 4];
  __shared__ float abuf[32 * 12];
  __shared__ float lred[32 * 8];
  __shared__ float lgb[512];

  const int tid = threadIdx.x;
  const int l = tid & 63;
  const int w = tid >> 6;
  const int l15 = l & 15, l16 = l >> 4;
  const int r0 = blockIdx.x * 32;

  lgb[tid] = lng[tid];
  lgb[256 + tid] = lnb[tid];

  // ---------------- GEMM1: T = z @ Wz ----------------
  const int row_s = tid >> 3, q_s = tid & 7;
  const float* zrow = z + (size_t)(r0 + row_s) * BD + q_s * 4;
  float4 zv = *(const float4*)(zrow);
  const uint4* wzf = (const uint4*)(ws + WS_WZF);

  f32x4 zero4 = {0.f, 0.f, 0.f, 0.f};
  f32x4 acc[2][4];
#pragma unroll
  for (int rt = 0; rt < 2; ++rt)
#pragma unroll
    for (int j = 0; j < 4; ++j) acc[rt][j] = zero4;

  for (int kt = 0; kt < 8; ++kt) {
    unsigned int p01 = (unsigned int)f2bf(zv.x) | ((unsigned int)f2bf(zv.y) << 16);
    unsigned int p23 = (unsigned int)f2bf(zv.z) | ((unsigned int)f2bf(zv.w) << 16);
    unsigned int* dw = (unsigned int*)&zs[row_s * 40 + q_s * 4];
    dw[0] = p01; dw[1] = p23;
    __syncthreads();
    if (kt < 7) zv = *(const float4*)(zrow + (kt + 1) * 32);
    uint4 ua0 = *(const uint4*)&zs[l15 * 40 + l16 * 8];
    uint4 ua1 = *(const uint4*)&zs[(16 + l15) * 40 + l16 * 8];
    bf16x8 a0 = __builtin_bit_cast(bf16x8, ua0);
    bf16x8 a1 = __builtin_bit_cast(bf16x8, ua1);
#pragma unroll
    for (int j = 0; j < 4; ++j) {
      uint4 ub = wzf[(kt * 16 + (w * 4 + j)) * 64 + l];
      bf16x8 b = __builtin_bit_cast(bf16x8, ub);
      acc[0][j] = __builtin_amdgcn_mfma_f32_16x16x32_bf16(a0, b, acc[0][j], 0, 0, 0);
      acc[1][j] = __builtin_amdgcn_mfma_f32_16x16x32_bf16(a1, b, acc[1][j], 0, 0, 0);
    }
    __syncthreads();
  }
  // write T (bf16), stride 264 halfs
#pragma unroll
  for (int rt = 0; rt < 2; ++rt)
#pragma unroll
    for (int j = 0; j < 4; ++j)
#pragma unroll
      for (int r = 0; r < 4; ++r) {
        int row = rt * 16 + l16 * 4 + r;
        int col = (w * 4 + j) * 16 + l15;
        U[row * 264 + col] = f2bf(acc[rt][j][r]);
      }
  __syncthreads();

  // ---------------- E1: exact fp32 router + alpha softmax ----------------
  {
    const int row = tid >> 3, seg = tid & 7;
    const float* zr = z + (size_t)(r0 + row) * BD + seg * 32;
    float l0 = 0.f, l1 = 0.f, l2 = 0.f;
#pragma unroll
    for (int jj = 0; jj < 32; jj += 4) {
      float4 zv4 = *(const float4*)(zr + jj);
      float4 w0 = *(const float4*)(wg + 0 * BD + seg * 32 + jj);
      float4 w1 = *(const float4*)(wg + 1 * BD + seg * 32 + jj);
      float4 w2 = *(const float4*)(wg + 2 * BD + seg * 32 + jj);
      l0 = fmaf(zv4.x, w0.x, fmaf(zv4.y, w0.y, fmaf(zv4.z, w0.z, fmaf(zv4.w, w0.w, l0))));
      l1 = fmaf(zv4.x, w1.x, fmaf(zv4.y, w1.y, fmaf(zv4.z, w1.z, fmaf(zv4.w, w1.w, l1))));
      l2 = fmaf(zv4.x, w2.x, fmaf(zv4.y, w2.y, fmaf(zv4.z, w2.z, fmaf(zv4.w, w2.w, l2))));
    }
#pragma unroll
    for (int mk = 1; mk < 8; mk <<= 1) {
      l0 += __shfl_xor(l0, mk, 64);
      l1 += __shfl_xor(l1, mk, 64);
      l2 += __shfl_xor(l2, mk, 64);
    }
    if (seg == 0) {
      l0 += bg[0]; l1 += bg[1]; l2 += bg[2];
      float mx = fmaxf(l0, fmaxf(l1, l2));
      float e0 = __expf(l0 - mx), e1 = __expf(l1 - mx), e2 = __expf(l2 - mx);
      float inv = 1.0f / (e0 + e1 + e2);
      float p0 = e0 * inv, p1 = e1 * inv, p2 = e2 * inv;
      int drop = (p2 <= p1 && p2 <= p0) ? 2 : ((p1 <= p0) ? 1 : 0);
      float a = (drop == 0) ? 0.f : p0;
      float b = (drop == 1) ? 0.f : p1;
      float c = (drop == 2) ? 0.f : p2;
      float den = 1.0f / (a + b + c + 1e-9f);
      rbuf[row * 4 + 0] = a * den; rbuf[row * 4 + 1] = b * den; rbuf[row * 4 + 2] = c * den;
#pragma unroll
      for (int n = 0; n < 3; ++n)
#pragma unroll
        for (int lv = 0; lv < 2; ++lv) {
          float sc[8]; float mx2 = -1e30f;
#pragma unroll
          for (int p = 0; p < 8; ++p) { sc[p] = bf2f(U[row * 264 + 3 + n * 16 + lv * 8 + p]); mx2 = fmaxf(mx2, sc[p]); }
          float sum = 0.f;
#pragma unroll
          for (int p = 0; p < 8; ++p) { sc[p] = __expf(sc[p] - mx2); sum += sc[p]; }
          float lwv = ws[WS_LW + n * 2 + lv] / sum;
#pragma unroll
          for (int p = 0; p < 8; ++p) cbuf[row * 48 + n * 16 + lv * 8 + p] = sc[p] * lwv;
        }
    }
  }
  __syncthreads();

  // ---------------- E2: attention logits + softmax ----------------
  if (tid < 128) {
    int row = tid >> 2, h = tid & 3;
    const float* bq = ws + WS_BQK + h * 64;
    int tb = row * 264 + 51 + h * 49;
    float atk[3];
#pragma unroll
    for (int n = 0; n < 3; ++n) {
      float s = 0.f;
#pragma unroll
      for (int i = 0; i < 16; ++i)
        s = fmaf(cbuf[row * 48 + n * 16 + i], bf2f(U[tb + n * 16 + i]) + bq[n * 16 + i], s);
      atk[n] = s;
    }
    float cb = bf2f(U[tb + 48]) + bq[48];
    float a0 = atk[0] + cb, a1 = atk[1] + cb, a2 = atk[2] + cb;
    float mx = fmaxf(a0, fmaxf(a1, a2));
    float e0 = __expf(a0 - mx), e1 = __expf(a1 - mx), e2 = __expf(a2 - mx);
    float inv = 1.0f / (e0 + e1 + e2);
    abuf[(row * 4 + h) * 3 + 0] = e0 * inv;
    abuf[(row * 4 + h) * 3 + 1] = e1 * inv;
    abuf[(row * 4 + h) * 3 + 2] = e2 * inv;
  }
  __syncthreads();

  // ---------------- E3: build G (hi/lo bf16, XOR-swizzled, vectorized writes) ----------------
  if (tid < 128) {
    int row = tid >> 2, h = tid & 3;
    int xr = (row & 7) << 3;
    int base = row * 256;
    const float* cb = cbuf + row * 48;
    const float* ab = abuf + (row * 4 + h) * 3;
#pragma unroll
    for (int g = 0; g < 6; ++g) {
      float an = ab[g >> 1];
      unsigned int ph[4], pl[4];
#pragma unroll
      for (int q2 = 0; q2 < 4; ++q2) {
        float g0 = an * cb[g * 8 + q2 * 2 + 0];
        float g1 = an * cb[g * 8 + q2 * 2 + 1];
        unsigned short h0 = f2bf(g0), h1 = f2bf(g1);
        unsigned short e0 = f2bf(g0 - bf2f(h0)), e1 = f2bf(g1 - bf2f(h1));
        ph[q2] = (unsigned int)h0 | ((unsigned int)h1 << 16);
        pl[q2] = (unsigned int)e0 | ((unsigned int)e1 << 16);
      }
      int k0 = (h * 48 + g * 8) ^ xr;     // 8-aligned base, XOR hits bits 3-5 -> stays 8-aligned
      *(uint4*)&U[base + k0] = make_uint4(ph[0], ph[1], ph[2], ph[3]);
      *(uint4*)&U[8192 + base + k0] = make_uint4(pl[0], pl[1], pl[2], pl[3]);
    }
  } else if (tid < 160) {
    int row = tid - 128;
    int xr = (row & 7) << 3;
    int base = row * 256;
    const float* cb = cbuf + row * 48;
    const float* rb = rbuf + row * 4;
#pragma unroll
    for (int g = 0; g < 6; ++g) {
      float rn = rb[g >> 1];
      unsigned int ph[4], pl[4];
#pragma unroll
      for (int q2 = 0; q2 < 4; ++q2) {
        float g0 = rn * cb[g * 8 + q2 * 2 + 0];
        float g1 = rn * cb[g * 8 + q2 * 2 + 1];
        unsigned short h0 = f2bf(g0), h1 = f2bf(g1);
        unsigned short e0 = f2bf(g0 - bf2f(h0)), e1 = f2bf(g1 - bf2f(h1));
        ph[q2] = (unsigned int)h0 | ((unsigned int)h1 << 16);
        pl[q2] = (unsigned int)e0 | ((unsigned int)e1 << 16);
      }
      int k0 = (192 + g * 8) ^ xr;
      *(uint4*)&U[base + k0] = make_uint4(ph[0], ph[1], ph[2], ph[3]);
      *(uint4*)&U[8192 + base + k0] = make_uint4(pl[0], pl[1], pl[2], pl[3]);
    }
    int k240 = (240) ^ xr;                 // OB row: G=1 (hi), 0 (lo); zero-fill k=241..247
    *(uint4*)&U[base + k240] = make_uint4(0x3f80u, 0u, 0u, 0u);
    *(uint4*)&U[8192 + base + k240] = make_uint4(0u, 0u, 0u, 0u);
    int k248 = (248) ^ xr;                 // zero-fill k=248..255 (avoid NaN garbage into MFMA)
    *(uint4*)&U[base + k248] = make_uint4(0u, 0u, 0u, 0u);
    *(uint4*)&U[8192 + base + k248] = make_uint4(0u, 0u, 0u, 0u);
  }
  __syncthreads();

  // ---------------- GEMM3: y = G @ M (G split hi/lo) ----------------
  f32x4 acc3[2][4];
#pragma unroll
  for (int rt = 0; rt < 2; ++rt)
#pragma unroll
    for (int j = 0; j < 4; ++j) acc3[rt][j] = zero4;
  const uint4* mf = (const uint4*)(ws + WS_MF);
  for (int kt = 0; kt < 8; ++kt) {
    uint4 uah[2], ual[2];
#pragma unroll
    for (int rt = 0; rt < 2; ++rt) {
      int row = rt * 16 + l15;
      int hidx = row * 256 + ((kt * 32 + l16 * 8) ^ ((row & 7) << 3));
      uah[rt] = *(const uint4*)&U[hidx];
      ual[rt] = *(const uint4*)&U[8192 + hidx];
    }
#pragma unroll
    for (int j = 0; j < 4; ++j) {
      uint4 ub = mf[(kt * 16 + w * 4 + j) * 64 + l];
      bf16x8 b = __builtin_bit_cast(bf16x8, ub);
#pragma unroll
      for (int rt = 0; rt < 2; ++rt) {
        acc3[rt][j] = __builtin_amdgcn_mfma_f32_16x16x32_bf16(__builtin_bit_cast(bf16x8, uah[rt]), b, acc3[rt][j], 0, 0, 0);
        acc3[rt][j] = __builtin_amdgcn_mfma_f32_16x16x32_bf16(__builtin_bit_cast(bf16x8, ual[rt]), b, acc3[rt][j], 0, 0, 0);
      }
    }
  }

  // ---------------- LN (fused) ----------------
  float sm[2][4], sq[2][4];
#pragma unroll
  for (int rt = 0; rt < 2; ++rt)
#pragma unroll
    for (int r = 0; r < 4; ++r) {
      float s = 0.f, q2 = 0.f;
#pragma unroll
      for (int j = 0; j < 4; ++j) { float v = acc3[rt][j][r]; s += v; q2 = fmaf(v, v, q2); }
      sm[rt][r] = s; sq[rt][r] = q2;
    }
#pragma unroll
  for (int mk = 1; mk < 16; mk <<= 1)
#pragma unroll
    for (int rt = 0; rt < 2; ++rt)
#pragma unroll
      for (int r = 0; r < 4; ++r) {
        sm[rt][r] += __shfl_xor(sm[rt][r], mk, 64);
        sq[rt][r] += __shfl_xor(sq[rt][r], mk, 64);
      }
  if (l15 == 0) {
#pragma unroll
    for (int rt = 0; rt < 2; ++rt)
#pragma unroll
      for (int r = 0; r < 4; ++r) {
        int row = rt * 16 + l16 * 4 + r;
        lred[(row * 4 + w) * 2 + 0] = sm[rt][r];
        lred[(row * 4 + w) * 2 + 1] = sq[rt][r];
      }
  }
  __syncthreads();
#pragma unroll
  for (int rt = 0; rt < 2; ++rt)
#pragma unroll
    for (int r = 0; r < 4; ++r) {
      int row = rt * 16 + l16 * 4 + r;
      float ts = lred[(row * 4 + 0) * 2] + lred[(row * 4 + 1) * 2] + lred[(row * 4 + 2) * 2] + lred[(row * 4 + 3) * 2];
      float tq = lred[(row * 4 + 0) * 2 + 1] + lred[(row * 4 + 1) * 2 + 1] + lred[(row * 4 + 2) * 2 + 1] + lred[(row * 4 + 3) * 2 + 1];
      float mu = ts * (1.0f / 256.0f);
      float var = tq * (1.0f / 256.0f) - mu * mu;
      float rstd = rsqrtf(var + 1e-5f);
#pragma unroll
      for (int j = 0; j < 4; ++j) {
        int col = (w * 4 + j) * 16 + l15;
        float v = (acc3[rt][j][r] - mu) * rstd * lgb[col] + lgb[256 + col];
        out[(size_t)(r0 + row) * BD + col] = v;
      }
    }
}

extern "C" void kernel_launch(void* const* d_in, const int* in_sizes, int n_in,
                              void* d_out, int out_size, void* d_ws, size_t ws_size,
                              hipStream_t stream) {
  const float* z     = (const float*)d_in[0];
  const float* prims = (const float*)d_in[1];
  const float* lvlw  = (const float*)d_in[2];
  const float* wq    = (const float*)d_in[3];
  const float* wg    = (const float*)d_in[4];
  const float* bg    = (const float*)d_in[5];
  const float* ipw   = (const float*)d_in[6];
  const float* ipb   = (const float*)d_in[7];
  const float* outw  = (const float*)d_in[8];
  const float* outb  = (const float*)d_in[9];
  const float* lng   = (const float*)d_in[10];
  const float* lnb   = (const float*)d_in[11];
  const float* caw   = (const float*)d_in[12];
  float* wsf = (float*)d_ws;
  float* out = (float*)d_out;

  if (ws_size < (size_t)WS_TOTAL * sizeof(float)) return;  // 727 KB <= proven-available 740 KB

  const int B = in_sizes[0] / BD;   // 65536
  hpm_k0a<<<145, 256, 0, stream>>>(prims, lvlw, wq, ipw, ipb, outw, outb, caw, wsf);
  hpm_k0b<<<389, 256, 0, stream>>>(ipw, ipb, outw, caw, wsf);
  hpm_k0c1<<<256, 256, 0, stream>>>(wg, wsf);
  hpm_k0c2<<<256, 256, 0, stream>>>(wsf);
  hpm_main<<<B / 32, 256, 0, stream>>>(z, wg, bg, lng, lnb, wsf, out);
}

// Round 5
// 212.629 us; speedup vs baseline: 4.2088x; 1.1700x over previous
//
#include <hip/hip_runtime.h>

#define BD 256

// ---- ws offsets (floats), total 102928 floats = 412 KB ----
#define WS_PQ   0         // [48][256]  (prims@Wq)/16   (pre1 -> pre2)
#define WS_MF   12288     // 65536 halfs: M  bf16 B-fragments
#define WS_WZF  45056     // 65536 halfs: Wz bf16 B-fragments
#define WS_OB   77824     // [256]      m*(bv@out_w^T + out_b)
#define WS_BQK  78080     // [4][64]    bq-side constants /8
#define WS_LW   78336     // [16]       softmax(level_weights)
#define WS_KP   78352     // [48][256]  prims@Wk^T (pre1 -> pre2)
#define WS_VP   90640     // [48][256]  prims@Wv^T (pre1 -> pre2)
#define WS_TOTAL 102928

typedef __bf16 bf16x8 __attribute__((ext_vector_type(8)));
typedef float  f32x4  __attribute__((ext_vector_type(4)));

__device__ __forceinline__ float bf2f(unsigned short u) {
  union { float f; unsigned int i; } c; c.i = ((unsigned int)u) << 16; return c.f;
}
__device__ __forceinline__ unsigned short f2bf(float f) {
  union { float f; unsigned int i; } c; c.f = f;
  unsigned int x = c.i;
  unsigned int r = (x + 0x7fffu + ((x >> 16) & 1u)) >> 16;
  return (unsigned short)r;
}
// B-fragment half-index for X[k][col] (16x16x32 bf16 B operand):
// e = ((kt*16+ct)*64 + lane)*8 + i, k = kt*32+(lane>>4)*8+i, col = ct*16+(lane&15)
__device__ __forceinline__ int frag_idx(int k, int col) {
  return (((k >> 5) * 16 + (col >> 4)) * 64 + (((k >> 3) & 3) * 16 + (col & 15))) * 8 + (k & 7);
}

// ---------------- pre1: Kp, Vp, PQ, OB, LW ----------------
__global__ void hpm_pre1(const float* __restrict__ prims, const float* __restrict__ lvlw,
                         const float* __restrict__ wq, const float* __restrict__ ipw,
                         const float* __restrict__ ipb, const float* __restrict__ outw,
                         const float* __restrict__ outb, const float* __restrict__ caw,
                         float* __restrict__ ws) {
  int t = threadIdx.x, blk = blockIdx.x;
  float m = 1.0f / (1.0f + __expf(-caw[0]));
  if (blk < 96) {                    // Kp[nlp][o]=prims.Wk_row(o) ; Vp likewise
    int nlp = (blk < 48) ? blk : blk - 48;
    const float4* pr = (const float4*)(prims + nlp * BD);
    const float4* wr = (const float4*)(ipw + (size_t)((blk < 48 ? 256 : 512) + t) * BD);
    float s0 = 0.f, s1 = 0.f, s2 = 0.f, s3 = 0.f;
#pragma unroll 8
    for (int i = 0; i < 64; ++i) {
      float4 p = pr[i], wv = wr[i];
      s0 = fmaf(p.x, wv.x, s0); s1 = fmaf(p.y, wv.y, s1);
      s2 = fmaf(p.z, wv.z, s2); s3 = fmaf(p.w, wv.w, s3);
    }
    ws[(blk < 48 ? WS_KP : WS_VP) + nlp * BD + t] = (s0 + s1) + (s2 + s3);
  } else if (blk < 144) {            // PQ[nlp][t] = (prims@Wq[n])/16
    int nlp = blk - 96, n = nlp >> 4;
    const float* pr = prims + nlp * BD;
    const float* wqn = wq + (size_t)n * BD * BD + t;
    float s0 = 0.f, s1 = 0.f, s2 = 0.f, s3 = 0.f;
#pragma unroll 4
    for (int o = 0; o < BD; o += 4) {
      s0 = fmaf(pr[o + 0], wqn[(size_t)(o + 0) * BD], s0);
      s1 = fmaf(pr[o + 1], wqn[(size_t)(o + 1) * BD], s1);
      s2 = fmaf(pr[o + 2], wqn[(size_t)(o + 2) * BD], s2);
      s3 = fmaf(pr[o + 3], wqn[(size_t)(o + 3) * BD], s3);
    }
    ws[WS_PQ + nlp * BD + t] = ((s0 + s1) + (s2 + s3)) * (1.0f / 16.0f);
  } else {                           // blk==144: OB + LW
    const float4* bv = (const float4*)(ipb + 512);
    const float4* orow = (const float4*)(outw + (size_t)t * BD);
    float s0 = 0.f, s1 = 0.f, s2 = 0.f, s3 = 0.f;
#pragma unroll 8
    for (int i = 0; i < 64; ++i) {
      float4 p = bv[i], wv = orow[i];
      s0 = fmaf(p.x, wv.x, s0); s1 = fmaf(p.y, wv.y, s1);
      s2 = fmaf(p.z, wv.z, s2); s3 = fmaf(p.w, wv.w, s3);
    }
    ws[WS_OB + t] = m * (((s0 + s1) + (s2 + s3)) + outb[t]);
    if (t == 0) {
      for (int n = 0; n < 3; ++n) {
        float a = lvlw[n * 2], b = lvlw[n * 2 + 1];
        float mx = fmaxf(a, b);
        float ea = __expf(a - mx), eb = __expf(b - mx);
        float inv = 1.0f / (ea + eb);
        ws[WS_LW + n * 2] = ea * inv;
        ws[WS_LW + n * 2 + 1] = eb * inv;
      }
      ws[WS_LW + 6] = 0.f; ws[WS_LW + 7] = 0.f;
    }
  }
}

// ---------------- pre2: KWT/CT direct-to-fragment, BQK, Wz/M pack ----------------
__global__ void hpm_pre2(const float* __restrict__ prims, const float* __restrict__ wg,
                         const float* __restrict__ ipw, const float* __restrict__ ipb,
                         const float* __restrict__ outw, const float* __restrict__ caw,
                         float* __restrict__ ws) {
  int t = threadIdx.x, blk = blockIdx.x;
  float m = 1.0f / (1.0f + __expf(-caw[0]));
  unsigned short* WZ = (unsigned short*)(ws + WS_WZF);
  unsigned short* MF = (unsigned short*)(ws + WS_MF);
  if (blk < 192) {                   // KW'[t][h][nlp]/8 -> Wz frag (k=t, col=51+h*49+nlp)
    int h = blk / 48, nlp = blk % 48;
    const float* kpr = ws + WS_KP + nlp * BD + h * 64;
    const float* ip = ipw + (size_t)(h * 64) * BD + t;
    float s0 = 0.f, s1 = 0.f, s2 = 0.f, s3 = 0.f;
#pragma unroll 4
    for (int o = 0; o < 64; o += 4) {
      s0 = fmaf(ip[(size_t)(o + 0) * BD], kpr[o + 0], s0);
      s1 = fmaf(ip[(size_t)(o + 1) * BD], kpr[o + 1], s1);
      s2 = fmaf(ip[(size_t)(o + 2) * BD], kpr[o + 2], s2);
      s3 = fmaf(ip[(size_t)(o + 3) * BD], kpr[o + 3], s3);
    }
    WZ[frag_idx(t, 51 + h * 49 + nlp)] = f2bf(((s0 + s1) + (s2 + s3)) * 0.125f);
  } else if (blk < 196) {            // bias col (k=t, col=51+h*49+48)
    int h = blk - 192;
    const float* bk = ipb + 256 + h * 64;
    const float* ip = ipw + (size_t)(h * 64) * BD + t;
    float s = 0.f;
#pragma unroll 4
    for (int o = 0; o < 64; ++o) s = fmaf(ip[(size_t)o * BD], bk[o], s);
    WZ[frag_idx(t, 51 + h * 49 + 48)] = f2bf(s * 0.125f);
  } else if (blk < 388) {            // CT -> M frag (k=h*48+nlp, col=t)
    int q = blk - 196;
    int h = q / 48, nlp = q % 48;
    const float4* vp = (const float4*)(ws + WS_VP + nlp * BD + h * 64);
    const float4* orow = (const float4*)(outw + (size_t)t * BD + h * 64);
    float s0 = 0.f, s1 = 0.f, s2 = 0.f, s3 = 0.f;
#pragma unroll 8
    for (int i = 0; i < 16; ++i) {
      float4 p = vp[i], wv = orow[i];
      s0 = fmaf(p.x, wv.x, s0); s1 = fmaf(p.y, wv.y, s1);
      s2 = fmaf(p.z, wv.z, s2); s3 = fmaf(p.w, wv.w, s3);
    }
    MF[frag_idx(h * 48 + nlp, t)] = f2bf(m * ((s0 + s1) + (s2 + s3)));
  } else if (blk == 388) {           // BQK
    if (t < 196) {
      int h = t / 49, j = t % 49;
      const float* bq = ipb + h * 64;
      float s = 0.f;
      if (j < 48) {
        const float* kpr = ws + WS_KP + j * BD + h * 64;
        for (int o = 0; o < 64; ++o) s = fmaf(bq[o], kpr[o], s);
      } else {
        const float* bk = ipb + 256 + h * 64;
        for (int o = 0; o < 64; ++o) s = fmaf(bq[o], bk[o], s);
      }
      ws[WS_BQK + h * 64 + j] = s * 0.125f;
    }
  } else if (blk < 440) {            // Wz cols 0..50 (wg rows + PQ)
    int col = blk - 389;
    float v = (col < 3) ? wg[col * BD + t] : ws[WS_PQ + (col - 3) * BD + t];
    WZ[frag_idx(t, col)] = f2bf(v);
  } else if (blk == 440) {           // Wz zero cols 247..255
#pragma unroll
    for (int c = 247; c < 256; ++c) WZ[frag_idx(t, c)] = 0;
  } else if (blk < 489) {            // M rows 192..239 = (1-m)*prims^T
    int i = blk - 441;
    MF[frag_idx(192 + i, t)] = f2bf((1.0f - m) * prims[i * BD + t]);
  } else {                           // blk==489: M row 240 = OB, rows 241..255 zero
    MF[frag_idx(240, t)] = f2bf(ws[WS_OB + t]);
#pragma unroll
    for (int k = 241; k < 256; ++k) MF[frag_idx(k, t)] = 0;
  }
}

// ---------------- main: stage+router -> GEMM1 (barrier-free) -> softmaxes -> GEMM3 -> LN ----------------
__global__ __launch_bounds__(256) void hpm_main(
    const float* __restrict__ z, const float* __restrict__ wg,
    const float* __restrict__ bg, const float* __restrict__ lng,
    const float* __restrict__ lnb, const float* __restrict__ ws,
    float* __restrict__ out) {
  // SB phase1: zbf [32][264] @0, T [32][264] @8448 ; phase2: Gh @0, Gl @8192
  __shared__ unsigned short SB[16896];
  __shared__ float cbuf[32 * 48];
  __shared__ float rbuf[32 * 4];
  __shared__ float abuf[32 * 12];
  __shared__ float lred[32 * 8];
  __shared__ float lgb[512];

  const int tid = threadIdx.x;
  const int l = tid & 63;
  const int w = tid >> 6;
  const int l15 = l & 15, l16 = l >> 4;
  const int r0 = blockIdx.x * 32;

  lgb[tid] = lng[tid];
  lgb[256 + tid] = lnb[tid];

  // ---- stage z -> LDS bf16 [32][264], fused exact fp32 router partials ----
  {
    const int srow = tid >> 3, seg = tid & 7;
    const float* zr = z + (size_t)(r0 + srow) * BD + seg * 32;
    float l0 = 0.f, l1 = 0.f, l2 = 0.f;
    unsigned int pk[16];
#pragma unroll
    for (int j = 0; j < 8; ++j) {
      float4 zv = ((const float4*)zr)[j];
      const float* wgp = wg + seg * 32 + j * 4;
      float4 w0 = *(const float4*)(wgp);
      float4 w1 = *(const float4*)(wgp + BD);
      float4 w2 = *(const float4*)(wgp + 2 * BD);
      l0 = fmaf(zv.x, w0.x, fmaf(zv.y, w0.y, fmaf(zv.z, w0.z, fmaf(zv.w, w0.w, l0))));
      l1 = fmaf(zv.x, w1.x, fmaf(zv.y, w1.y, fmaf(zv.z, w1.z, fmaf(zv.w, w1.w, l1))));
      l2 = fmaf(zv.x, w2.x, fmaf(zv.y, w2.y, fmaf(zv.z, w2.z, fmaf(zv.w, w2.w, l2))));
      pk[j * 2 + 0] = (unsigned int)f2bf(zv.x) | ((unsigned int)f2bf(zv.y) << 16);
      pk[j * 2 + 1] = (unsigned int)f2bf(zv.z) | ((unsigned int)f2bf(zv.w) << 16);
    }
    unsigned short* zl = &SB[srow * 264 + seg * 32];
#pragma unroll
    for (int q = 0; q < 4; ++q)
      *(uint4*)(zl + q * 8) = make_uint4(pk[q * 4], pk[q * 4 + 1], pk[q * 4 + 2], pk[q * 4 + 3]);
#pragma unroll
    for (int mk = 1; mk < 8; mk <<= 1) {
      l0 += __shfl_xor(l0, mk, 64);
      l1 += __shfl_xor(l1, mk, 64);
      l2 += __shfl_xor(l2, mk, 64);
    }
    if (seg == 0) {
      l0 += bg[0]; l1 += bg[1]; l2 += bg[2];
      float mx = fmaxf(l0, fmaxf(l1, l2));
      float e0 = __expf(l0 - mx), e1 = __expf(l1 - mx), e2 = __expf(l2 - mx);
      float inv = 1.0f / (e0 + e1 + e2);
      float p0 = e0 * inv, p1 = e1 * inv, p2 = e2 * inv;
      int drop = (p2 <= p1 && p2 <= p0) ? 2 : ((p1 <= p0) ? 1 : 0);
      float a = (drop == 0) ? 0.f : p0;
      float b = (drop == 1) ? 0.f : p1;
      float c = (drop == 2) ? 0.f : p2;
      float den = 1.0f / (a + b + c + 1e-9f);
      rbuf[srow * 4 + 0] = a * den; rbuf[srow * 4 + 1] = b * den; rbuf[srow * 4 + 2] = c * den;
    }
  }
  __syncthreads();

  // ---- GEMM1: T = z @ Wz (barrier-free k-loop from read-only LDS) ----
  f32x4 zero4 = {0.f, 0.f, 0.f, 0.f};
  f32x4 acc[2][4];
#pragma unroll
  for (int rt = 0; rt < 2; ++rt)
#pragma unroll
    for (int j = 0; j < 4; ++j) acc[rt][j] = zero4;
  const uint4* wzf = (const uint4*)(ws + WS_WZF);
#pragma unroll
  for (int kt = 0; kt < 8; ++kt) {
    bf16x8 a0 = __builtin_bit_cast(bf16x8, *(const uint4*)&SB[l15 * 264 + kt * 32 + l16 * 8]);
    bf16x8 a1 = __builtin_bit_cast(bf16x8, *(const uint4*)&SB[(16 + l15) * 264 + kt * 32 + l16 * 8]);
#pragma unroll
    for (int j = 0; j < 4; ++j) {
      bf16x8 b = __builtin_bit_cast(bf16x8, wzf[(kt * 16 + (w * 4 + j)) * 64 + l]);
      acc[0][j] = __builtin_amdgcn_mfma_f32_16x16x32_bf16(a0, b, acc[0][j], 0, 0, 0);
      acc[1][j] = __builtin_amdgcn_mfma_f32_16x16x32_bf16(a1, b, acc[1][j], 0, 0, 0);
    }
  }
#pragma unroll
  for (int rt = 0; rt < 2; ++rt)
#pragma unroll
    for (int j = 0; j < 4; ++j)
#pragma unroll
      for (int r = 0; r < 4; ++r) {
        int row = rt * 16 + l16 * 4 + r;
        int col = (w * 4 + j) * 16 + l15;
        SB[8448 + row * 264 + col] = f2bf(acc[rt][j][r]);
      }
  __syncthreads();

  // ---- alpha softmax: 192 threads, (row, n*2+lv) ----
  if (tid < 192) {
    int row = tid & 31, grp = tid >> 5;          // grp = n*2+lv
    const unsigned short* tb = &SB[8448 + row * 264 + 3 + grp * 8];
    float sc[8]; float mx = -1e30f;
#pragma unroll
    for (int p = 0; p < 8; ++p) { sc[p] = bf2f(tb[p]); mx = fmaxf(mx, sc[p]); }
    float sum = 0.f;
#pragma unroll
    for (int p = 0; p < 8; ++p) { sc[p] = __expf(sc[p] - mx); sum += sc[p]; }
    float lwv = ws[WS_LW + grp] / sum;
#pragma unroll
    for (int p = 0; p < 8; ++p) cbuf[row * 48 + grp * 8 + p] = sc[p] * lwv;
  }
  __syncthreads();

  // ---- E2: attention logits + softmax (128 threads: row, h) ----
  if (tid < 128) {
    int row = tid >> 2, h = tid & 3;
    const float* bq = ws + WS_BQK + h * 64;
    const unsigned short* tb = &SB[8448 + row * 264 + 51 + h * 49];
    float atk[3];
#pragma unroll
    for (int n = 0; n < 3; ++n) {
      float s = 0.f;
#pragma unroll
      for (int i = 0; i < 16; ++i)
        s = fmaf(cbuf[row * 48 + n * 16 + i], bf2f(tb[n * 16 + i]) + bq[n * 16 + i], s);
      atk[n] = s;
    }
    float cb = bf2f(tb[48]) + bq[48];
    float a0 = atk[0] + cb, a1 = atk[1] + cb, a2 = atk[2] + cb;
    float mx = fmaxf(a0, fmaxf(a1, a2));
    float e0 = __expf(a0 - mx), e1 = __expf(a1 - mx), e2 = __expf(a2 - mx);
    float inv = 1.0f / (e0 + e1 + e2);
    abuf[(row * 4 + h) * 3 + 0] = e0 * inv;
    abuf[(row * 4 + h) * 3 + 1] = e1 * inv;
    abuf[(row * 4 + h) * 3 + 2] = e2 * inv;
  }
  __syncthreads();

  // ---- E3: build G hi/lo bf16, XOR-swizzled, vectorized (overwrites zbf+T) ----
  if (tid < 128) {
    int row = tid >> 2, h = tid & 3;
    int xr = (row & 7) << 3;
    int base = row * 256;
    const float* cb = cbuf + row * 48;
    const float* ab = abuf + (row * 4 + h) * 3;
#pragma unroll
    for (int g = 0; g < 6; ++g) {
      float an = ab[g >> 1];
      unsigned int ph[4], pl[4];
#pragma unroll
      for (int q2 = 0; q2 < 4; ++q2) {
        float g0 = an * cb[g * 8 + q2 * 2 + 0];
        float g1 = an * cb[g * 8 + q2 * 2 + 1];
        unsigned short h0 = f2bf(g0), h1 = f2bf(g1);
        unsigned short e0 = f2bf(g0 - bf2f(h0)), e1 = f2bf(g1 - bf2f(h1));
        ph[q2] = (unsigned int)h0 | ((unsigned int)h1 << 16);
        pl[q2] = (unsigned int)e0 | ((unsigned int)e1 << 16);
      }
      int k0 = (h * 48 + g * 8) ^ xr;
      *(uint4*)&SB[base + k0] = make_uint4(ph[0], ph[1], ph[2], ph[3]);
      *(uint4*)&SB[8192 + base + k0] = make_uint4(pl[0], pl[1], pl[2], pl[3]);
    }
  } else if (tid < 160) {
    int row = tid - 128;
    int xr = (row & 7) << 3;
    int base = row * 256;
    const float* cb = cbuf + row * 48;
    const float* rb = rbuf + row * 4;
#pragma unroll
    for (int g = 0; g < 6; ++g) {
      float rn = rb[g >> 1];
      unsigned int ph[4], pl[4];
#pragma unroll
      for (int q2 = 0; q2 < 4; ++q2) {
        float g0 = rn * cb[g * 8 + q2 * 2 + 0];
        float g1 = rn * cb[g * 8 + q2 * 2 + 1];
        unsigned short h0 = f2bf(g0), h1 = f2bf(g1);
        unsigned short e0 = f2bf(g0 - bf2f(h0)), e1 = f2bf(g1 - bf2f(h1));
        ph[q2] = (unsigned int)h0 | ((unsigned int)h1 << 16);
        pl[q2] = (unsigned int)e0 | ((unsigned int)e1 << 16);
      }
      int k0 = (192 + g * 8) ^ xr;
      *(uint4*)&SB[base + k0] = make_uint4(ph[0], ph[1], ph[2], ph[3]);
      *(uint4*)&SB[8192 + base + k0] = make_uint4(pl[0], pl[1], pl[2], pl[3]);
    }
    int k240 = 240 ^ xr;
    *(uint4*)&SB[base + k240] = make_uint4(0x3f80u, 0u, 0u, 0u);
    *(uint4*)&SB[8192 + base + k240] = make_uint4(0u, 0u, 0u, 0u);
    int k248 = 248 ^ xr;
    *(uint4*)&SB[base + k248] = make_uint4(0u, 0u, 0u, 0u);
    *(uint4*)&SB[8192 + base + k248] = make_uint4(0u, 0u, 0u, 0u);
  }
  __syncthreads();

  // ---- GEMM3: y = G @ M (hi/lo) ----
  f32x4 acc3[2][4];
#pragma unroll
  for (int rt = 0; rt < 2; ++rt)
#pragma unroll
    for (int j = 0; j < 4; ++j) acc3[rt][j] = zero4;
  const uint4* mf = (const uint4*)(ws + WS_MF);
#pragma unroll
  for (int kt = 0; kt < 8; ++kt) {
    uint4 uah[2], ual[2];
#pragma unroll
    for (int rt = 0; rt < 2; ++rt) {
      int row = rt * 16 + l15;
      int hidx = row * 256 + ((kt * 32 + l16 * 8) ^ ((row & 7) << 3));
      uah[rt] = *(const uint4*)&SB[hidx];
      ual[rt] = *(const uint4*)&SB[8192 + hidx];
    }
#pragma unroll
    for (int j = 0; j < 4; ++j) {
      bf16x8 b = __builtin_bit_cast(bf16x8, mf[(kt * 16 + w * 4 + j) * 64 + l]);
#pragma unroll
      for (int rt = 0; rt < 2; ++rt) {
        acc3[rt][j] = __builtin_amdgcn_mfma_f32_16x16x32_bf16(__builtin_bit_cast(bf16x8, uah[rt]), b, acc3[rt][j], 0, 0, 0);
        acc3[rt][j] = __builtin_amdgcn_mfma_f32_16x16x32_bf16(__builtin_bit_cast(bf16x8, ual[rt]), b, acc3[rt][j], 0, 0, 0);
      }
    }
  }

  // ---- fused LN ----
  float sm[2][4], sq[2][4];
#pragma unroll
  for (int rt = 0; rt < 2; ++rt)
#pragma unroll
    for (int r = 0; r < 4; ++r) {
      float s = 0.f, q2 = 0.f;
#pragma unroll
      for (int j = 0; j < 4; ++j) { float v = acc3[rt][j][r]; s += v; q2 = fmaf(v, v, q2); }
      sm[rt][r] = s; sq[rt][r] = q2;
    }
#pragma unroll
  for (int mk = 1; mk < 16; mk <<= 1)
#pragma unroll
    for (int rt = 0; rt < 2; ++rt)
#pragma unroll
      for (int r = 0; r < 4; ++r) {
        sm[rt][r] += __shfl_xor(sm[rt][r], mk, 64);
        sq[rt][r] += __shfl_xor(sq[rt][r], mk, 64);
      }
  if (l15 == 0) {
#pragma unroll
    for (int rt = 0; rt < 2; ++rt)
#pragma unroll
      for (int r = 0; r < 4; ++r) {
        int row = rt * 16 + l16 * 4 + r;
        lred[(row * 4 + w) * 2 + 0] = sm[rt][r];
        lred[(row * 4 + w) * 2 + 1] = sq[rt][r];
      }
  }
  __syncthreads();
#pragma unroll
  for (int rt = 0; rt < 2; ++rt)
#pragma unroll
    for (int r = 0; r < 4; ++r) {
      int row = rt * 16 + l16 * 4 + r;
      float ts = lred[(row * 4 + 0) * 2] + lred[(row * 4 + 1) * 2] + lred[(row * 4 + 2) * 2] + lred[(row * 4 + 3) * 2];
      float tq = lred[(row * 4 + 0) * 2 + 1] + lred[(row * 4 + 1) * 2 + 1] + lred[(row * 4 + 2) * 2 + 1] + lred[(row * 4 + 3) * 2 + 1];
      float mu = ts * (1.0f / 256.0f);
      float var = tq * (1.0f / 256.0f) - mu * mu;
      float rstd = rsqrtf(var + 1e-5f);
#pragma unroll
      for (int j = 0; j < 4; ++j) {
        int col = (w * 4 + j) * 16 + l15;
        float v = (acc3[rt][j][r] - mu) * rstd * lgb[col] + lgb[256 + col];
        out[(size_t)(r0 + row) * BD + col] = v;
      }
    }
}

extern "C" void kernel_launch(void* const* d_in, const int* in_sizes, int n_in,
                              void* d_out, int out_size, void* d_ws, size_t ws_size,
                              hipStream_t stream) {
  const float* z     = (const float*)d_in[0];
  const float* prims = (const float*)d_in[1];
  const float* lvlw  = (const float*)d_in[2];
  const float* wq    = (const float*)d_in[3];
  const float* wg    = (const float*)d_in[4];
  const float* bg    = (const float*)d_in[5];
  const float* ipw   = (const float*)d_in[6];
  const float* ipb   = (const float*)d_in[7];
  const float* outw  = (const float*)d_in[8];
  const float* outb  = (const float*)d_in[9];
  const float* lng   = (const float*)d_in[10];
  const float* lnb   = (const float*)d_in[11];
  const float* caw   = (const float*)d_in[12];
  float* wsf = (float*)d_ws;
  float* out = (float*)d_out;

  if (ws_size < (size_t)WS_TOTAL * sizeof(float)) return;  // 412 KB

  const int B = in_sizes[0] / BD;   // 65536
  hpm_pre1<<<145, 256, 0, stream>>>(prims, lvlw, wq, ipw, ipb, outw, outb, caw, wsf);
  hpm_pre2<<<490, 256, 0, stream>>>(prims, wg, ipw, ipb, outw, caw, wsf);
  hpm_main<<<B / 32, 256, 0, stream>>>(z, wg, bg, lng, lnb, wsf, out);
}